// Round 11
// baseline (170.634 us; speedup 1.0000x reference)
//
#include <hip/hip_runtime.h>
#include <math.h>

#define BSZ   8
#define NSEQ  1024
#define DIM   512
#define NH    8
#define DH    64
#define INNER 512
#define NTOK  (BSZ*NSEQ)     // 8192
#define QKVN  (3*INNER)      // 1536

typedef __bf16   bf16x8 __attribute__((ext_vector_type(8)));
typedef _Float16 f16x8  __attribute__((ext_vector_type(8)));
typedef float    f32x4  __attribute__((ext_vector_type(4)));

// q pre-scale: softmax scale (DH^-0.5 = 0.125) folded with log2(e)
#define QSCL (0.125f * 1.44269504088896f)

static __device__ __forceinline__ ushort f2bf(float f) {
    union { float f; unsigned u; } v; v.f = f;
    unsigned r = (v.u + 0x7FFFu + ((v.u >> 16) & 1u)) >> 16;  // RNE
    return (ushort)r;
}
static __device__ __forceinline__ ushort f2h(float f) {
    _Float16 h = (_Float16)f;                                  // RNE
    return __builtin_bit_cast(unsigned short, h);
}
// async global->LDS DMA, 16B per lane; LDS dest = wave-uniform base + lane*16
static __device__ __forceinline__ void async16(const void* g, void* l) {
    __builtin_amdgcn_global_load_lds(
        (const __attribute__((address_space(1))) unsigned int*)g,
        (__attribute__((address_space(3))) unsigned int*)l, 16, 0, 0);
}

// ---------------------------------------------------------------------------
// Fused prep kernel: one dispatch.
//   blocks [0,4096):    x fp32 -> fp16
//   blocks [4096,4864): w_qkv [DIM][QKVN] -> wqT fp16 [QKVN][DIM]
//   blocks [4864,5120): w_out [INNER][DIM] -> woT bf16 [DIM][INNER]
// ---------------------------------------------------------------------------
__global__ __launch_bounds__(256) void prep_kernel(
    const float* __restrict__ x,  ushort* __restrict__ xf,
    const float* __restrict__ wq, ushort* __restrict__ wqT,
    const float* __restrict__ wo, ushort* __restrict__ woT)
{
    const int bid = blockIdx.x;
    if (bid < 4096) {
        const int i = bid*256 + threadIdx.x;
        float4 v = ((const float4*)x)[i];
        ushort4 h = { f2h(v.x), f2h(v.y), f2h(v.z), f2h(v.w) };
        ((ushort4*)xf)[i] = h;
        return;
    }
    __shared__ float tile[32][33];
    int K, F, bx, by; const float* in; ushort* outp; int is_q;
    if (bid < 4096 + 768) {
        const int id = bid - 4096;
        bx = id % 48; by = id / 48;          // F/32=48, K/32=16
        K = DIM; F = QKVN; in = wq; outp = wqT; is_q = 1;
    } else {
        const int id = bid - 4864;
        bx = id % 16; by = id / 16;          // F/32=16, K/32=16
        K = INNER; F = DIM; in = wo; outp = woT; is_q = 0;
    }
    const int lx = threadIdx.x & 31, ly = threadIdx.x >> 5;
#pragma unroll
    for (int u = 0; u < 4; u++) {
        const int k = by*32 + ly + u*8;
        tile[ly + u*8][lx] = in[(size_t)k*F + bx*32 + lx];
    }
    __syncthreads();
#pragma unroll
    for (int u = 0; u < 4; u++) {
        const int f = bx*32 + ly + u*8;
        const float v = tile[lx][ly + u*8];
        outp[(size_t)f*K + by*32 + lx] = is_q ? f2h(v) : f2bf(v);
    }
}

// ---------------------------------------------------------------------------
// Kernel 1 (R23 = R16 exact, proven in the session-best 164.7 total):
// qkv^T fp16 GEMM, DOUBLE-buffered LDS (2 x 16384 = 32768 B), BK=32,
// stage-before-wait, per-wave vmcnt(4). R21's triple-buffer rode along
// while "rest" time grew ~5-9us across rounds -> reverted on suspicion.
// Epilogue: bias + SE(3) pose.
// ---------------------------------------------------------------------------
__global__ __launch_bounds__(256) void qkv_gemm_f16(
    const ushort* __restrict__ Ag,   // wqT fp16 [QKVN][DIM]
    const ushort* __restrict__ Bg,   // x   fp16 [NTOK][DIM]
    const float* __restrict__ bias, const float* __restrict__ rot,
    const float* __restrict__ trans,
    ushort* __restrict__ qb, ushort* __restrict__ kb, ushort* __restrict__ vt)
{
    extern __shared__ __align__(16) char smem[];   // 32768 B

    const int tid  = threadIdx.x;
    const int lane = tid & 63;
    const int w    = tid >> 6;
    const int c    = lane & 15;
    const int quad = lane >> 4;
    const int wr   = w >> 1, wc = w & 1;
    const int tn   = blockIdx.x;   // token tile (64)
    const int tf   = blockIdx.y;   // feature tile (12)

    f32x4 acc[4][4] = {};

    // staging roles: part = w>>1 (0=A,1=B), group base = (w&1)*4
    const int part = w >> 1;
    const int g0   = (w & 1) * 4;
    const ushort* src = (part == 0) ? Ag : Bg;
    const ushort* wbase = src + (size_t)((part == 0 ? tf : tn)*128 + g0*16 + c)*DIM
                          + quad*8;

    auto stage = [&](int k0, int buf) {
#pragma unroll
        for (int g = 0; g < 4; g++)
            async16(wbase + (size_t)g*16*DIM + k0,
                    smem + buf*16384 + part*8192 + (g0 + g)*1024);
    };

    stage(0, 0);

    for (int ch = 0; ch < 16; ch++) {
        const int cur = ch & 1, nxt = cur ^ 1;
        if (ch < 15) {
            stage((ch+1)*32, nxt);
            // wait own chunk-ch's 4 DMAs (oldest); ch+1's 4 stay in flight
            __asm__ volatile("s_waitcnt vmcnt(4)\n\ts_barrier" ::: "memory");
        } else {
            __asm__ volatile("s_waitcnt vmcnt(0)\n\ts_barrier" ::: "memory");
        }

        const char* B = smem + cur*16384;
        f16x8 fa[4], fb[4];
#pragma unroll
        for (int i = 0; i < 4; i++)
            fa[i] = *(const f16x8*)(B + (wr*4 + i)*1024 + lane*16);
#pragma unroll
        for (int j = 0; j < 4; j++)
            fb[j] = *(const f16x8*)(B + 8192 + (wc*4 + j)*1024 + lane*16);
#pragma unroll
        for (int i = 0; i < 4; i++)
#pragma unroll
            for (int j = 0; j < 4; j++)
                acc[i][j] = __builtin_amdgcn_mfma_f32_16x16x32_f16(
                    fa[i], fb[j], acc[i][j], 0, 0, 0);
        __asm__ volatile("s_waitcnt lgkmcnt(0)\n\ts_barrier" ::: "memory");
    }

    // epilogue: bias + SE(3) pose + scatter (verified mapping, unchanged)
    const int sec = tf >> 2;          // 0=q 1=k 2=v (block-uniform)

#pragma unroll
    for (int j = 0; j < 4; j++) {
        const int tc = tn*128 + wc*64 + j*16 + c;
        const int bb = tc >> 10, n = tc & 1023;
        const float* R = rot   + (size_t)(bb*NSEQ + n)*9;
        const float* T = trans + (size_t)(bb*NSEQ + n)*3;
        const float R0=R[0],R1=R[1],R2=R[2],R3=R[3],R4=R[4],R5=R[5],R6=R[6],R7=R[7],R8=R[8];
        const float T0=T[0],T1=T[1],T2=T[2];
        float ti0 = 0.f, ti1 = 0.f, ti2 = 0.f;
        if (sec == 0) {
            ti0 = -(R0*T0 + R3*T1 + R6*T2);
            ti1 = -(R1*T0 + R4*T1 + R7*T2);
            ti2 = -(R2*T0 + R5*T1 + R8*T2);
        }
#pragma unroll
        for (int i = 0; i < 4; i++) {
            const int fr = tf*128 + wr*64 + i*16 + quad*4;
            const int fl = fr & 511;
            const int h  = fl >> 6, d = fl & 63;
            float4 bv = *(const float4*)(bias + fr);
            const float g0v = acc[i][j][0] + bv.x;
            const float g1v = acc[i][j][1] + bv.y;
            const float g2v = acc[i][j][2] + bv.z;
            const float g3v = acc[i][j][3] + bv.w;
            if (sec == 0) {
                float o0 = (R0*g0v + R1*g1v + R2*g2v) * QSCL;
                float o1 = (R3*g0v + R4*g1v + R5*g2v) * QSCL;
                float o2 = (R6*g0v + R7*g1v + R8*g2v) * QSCL;
                float o3 = (ti0*g0v + ti1*g1v + ti2*g2v + g3v) * QSCL;
                ushort4 ov = { f2bf(o0), f2bf(o1), f2bf(o2), f2bf(o3) };
                *(ushort4*)(qb + ((size_t)((bb*NH + h)*NSEQ + n))*DH + d) = ov;
            } else {
                float o0 = R0*g0v + R1*g1v + R2*g2v + T0*g3v;
                float o1 = R3*g0v + R4*g1v + R5*g2v + T1*g3v;
                float o2 = R6*g0v + R7*g1v + R8*g2v + T2*g3v;
                float o3 = g3v;
                if (sec == 1) {
                    ushort4 ov = { f2bf(o0), f2bf(o1), f2bf(o2), f2bf(o3) };
                    *(ushort4*)(kb + ((size_t)((bb*NH + h)*NSEQ + n))*DH + d) = ov;
                } else {
                    // v: write TRANSPOSED -> vt[bh][d][n]
                    ushort* vtb = vt + ((size_t)(bb*NH + h)*DH + d)*NSEQ + n;
                    vtb[0*NSEQ] = f2bf(o0);
                    vtb[1*NSEQ] = f2bf(o1);
                    vtb[2*NSEQ] = f2bf(o2);
                    vtb[3*NSEQ] = f2bf(o3);
                }
            }
        }
    }
}

// ---------------------------------------------------------------------------
// Kernel 2 (R23 = R21 exact, proven 49.7us): grid 1024 / 64-row Q-tiles /
// XCD swizzle / K+V LDS triple-buffer / ONE barrier per iter / counted
// vmcnt(4). R22's packed-b64 softmax reverted: it tripled LDS bank
// conflicts (589K -> 1.64M; 4-way aliasing at row stride 144B) and cost
// 1.3us despite lower VALU work.
// ---------------------------------------------------------------------------
__global__ __launch_bounds__(256, 2) void attn_mfma_kernel(
    const ushort* __restrict__ qb, const ushort* __restrict__ kb,
    const ushort* __restrict__ vt, const float* __restrict__ rot,
    const float* __restrict__ trans, ushort* __restrict__ om)
{
    __shared__ __align__(16) char smem[58368];   // KV 49152 + P 9216; Osh overlay

    const int tid  = threadIdx.x;
    const int lane = tid & 63;
    const int w    = tid >> 6;
    const int c    = lane & 15;
    const int quad = lane >> 4;

    // XCD-aware swizzle (nwg=1024, %8==0 -> bijective); 8 bh per XCD
    const int o   = blockIdx.x;               // 0..1023
    const int wid = (o & 7) * 128 + (o >> 3);
    const int qt  = wid & 15;                 // 0..15 (64 q rows each)
    const int bh  = wid >> 4;                 // 0..63
    const int bb = bh >> 3, h = bh & 7;

    const ushort* Q = qb + (size_t)bh * NSEQ * DH;
    const ushort* K = kb + (size_t)bh * NSEQ * DH;
    const ushort* V = vt + (size_t)bh * DH * NSEQ;   // [DH][NSEQ]

    // wave w owns q rows [qt*64 + w*16, +16)
    bf16x8 qf[2];
    {
        const ushort* qrow = Q + (size_t)(qt*64 + w*16 + c)*DH + quad*8;
        qf[0] = *(const bf16x8*)(qrow);
        qf[1] = *(const bf16x8*)(qrow + 32);
    }

    f32x4 Oacc[4] = {};
    float lsum[4] = {};

    // stage one 64-key chunk: 8 K segs + 8 V segs of 1024B; wave w issues
    // 2 of each (4 DMAs total per wave per chunk)
    auto stage = [&](int kt, int buf) {
#pragma unroll
        for (int u = 0; u < 2; u++) {            // K segs
            const int seg = w + u*4;             // 0..7
            const int nt = seg >> 1, hh = seg & 1;
            const ushort* g = K + (size_t)(kt*64 + nt*16 + c)*DH + hh*32 + quad*8;
            async16(g, smem + buf*16384 + seg*1024);
        }
#pragma unroll
        for (int u = 0; u < 2; u++) {            // V segs
            const int s2 = w + u*4;              // 0..7
            const int nt = s2 >> 1, kc = s2 & 1;
            const ushort* g = V + (size_t)(nt*16 + c)*NSEQ + kt*64 + kc*32 + quad*8;
            async16(g, smem + buf*16384 + 8192 + s2*1024);
        }
    };

    stage(0, 0);
    stage(1, 1);

    ushort (*Psw)[72] = (ushort (*)[72])(smem + 49152 + w*2304);

    for (int kt = 0; kt < 16; kt++) {
        const int cur = kt % 3;
        // own chunk-kt's 4 DMAs (oldest) done; kt+1's 4 stay in flight
        if (kt < 15) {
            __asm__ volatile("s_waitcnt vmcnt(4)\n\ts_barrier" ::: "memory");
        } else {
            __asm__ volatile("s_waitcnt vmcnt(0)\n\ts_barrier" ::: "memory");
        }
        // buf (kt+2)%3 == (kt-1)%3: its reads were consumed before
        // barrier(kt) (compiler lgkm waits precede the MFMAs that used them)
        if (kt < 14) stage(kt + 2, (kt + 2) % 3);

        const char* Kb = smem + cur*16384;
        const char* Vb = smem + cur*16384 + 8192;

        f32x4 s[4];
#pragma unroll
        for (int nt = 0; nt < 4; nt++) {
            bf16x8 k0 = *(const bf16x8*)(Kb + (nt*2+0)*1024 + lane*16);
            bf16x8 k1 = *(const bf16x8*)(Kb + (nt*2+1)*1024 + lane*16);
            f32x4 a = {0.f, 0.f, 0.f, 0.f};
            a = __builtin_amdgcn_mfma_f32_16x16x32_bf16(qf[0], k0, a, 0, 0, 0);
            a = __builtin_amdgcn_mfma_f32_16x16x32_bf16(qf[1], k1, a, 0, 0, 0);
            s[nt] = a;
        }

        // softmax numerator + P write (per-wave LDS region; same-wave DS
        // ops complete in order, no barrier needed)
#pragma unroll
        for (int nt = 0; nt < 4; nt++)
#pragma unroll
            for (int r = 0; r < 4; r++) {
                const float p = exp2f(s[nt][r]);
                lsum[r] += p;
                Psw[quad*4 + r][nt*16 + c] = (ushort)__builtin_bit_cast(
                    unsigned short, (__bf16)p);
            }
        __asm__ volatile("s_waitcnt lgkmcnt(0)" ::: "memory");

#pragma unroll
        for (int kc2 = 0; kc2 < 2; kc2++) {
            bf16x8 vfr[4];
#pragma unroll
            for (int nt = 0; nt < 4; nt++)
                vfr[nt] = *(const bf16x8*)(Vb + (nt*2+kc2)*1024 + lane*16);
            bf16x8 a = *(const bf16x8*)&Psw[c][kc2*32 + quad*8];
#pragma unroll
            for (int nt = 0; nt < 4; nt++)
                Oacc[nt] = __builtin_amdgcn_mfma_f32_16x16x32_bf16(
                    a, vfr[nt], Oacc[nt], 0, 0, 0);
        }
        // no trailing barrier: 3-buffer rotation gates KV reuse via the
        // top-of-loop barrier two iterations from now
    }

    // row sums: reduce across the 16 lanes sharing a quad (c varies)
#pragma unroll
    for (int mk = 1; mk < 16; mk <<= 1)
#pragma unroll
        for (int r = 0; r < 4; r++)
            lsum[r] += __shfl_xor(lsum[r], mk);

    __syncthreads();
    float (*Osh)[68] = (float (*)[68])smem;   // [64][68] = 17408 B overlay
    {
        float inv[4];
#pragma unroll
        for (int r = 0; r < 4; r++) inv[r] = 1.f / lsum[r];
#pragma unroll
        for (int nt = 0; nt < 4; nt++)
#pragma unroll
            for (int r = 0; r < 4; r++)
                Osh[w*16 + quad*4 + r][nt*16 + c] = Oacc[nt][r] * inv[r];
    }
    __syncthreads();

#pragma unroll
    for (int u = 0; u < 4; u++) {
        const int t   = tid + u*256;       // 0..1023
        const int row = t >> 4;            // 0..63
        const int g   = t & 15;
        const int n   = qt*64 + row;
        const float o0 = Osh[row][g*4+0], o1 = Osh[row][g*4+1];
        const float o2 = Osh[row][g*4+2], o3 = Osh[row][g*4+3];
        const float* R = rot   + (size_t)(bb*NSEQ + n)*9;
        const float* T = trans + (size_t)(bb*NSEQ + n)*3;
        const float ti0 = -(R[0]*T[0] + R[3]*T[1] + R[6]*T[2]);
        const float ti1 = -(R[1]*T[0] + R[4]*T[1] + R[7]*T[2]);
        const float ti2 = -(R[2]*T[0] + R[5]*T[1] + R[8]*T[2]);
        const float p0 = R[0]*o0 + R[3]*o1 + R[6]*o2 + ti0*o3;
        const float p1 = R[1]*o0 + R[4]*o1 + R[7]*o2 + ti1*o3;
        const float p2 = R[2]*o0 + R[5]*o1 + R[8]*o2 + ti2*o3;
        const float p3 = o3;
        ushort4 hv = { f2bf(p0), f2bf(p1), f2bf(p2), f2bf(p3) };
        *(ushort4*)(om + (size_t)(bb*NSEQ + n)*INNER + h*DH + g*4) = hv;
    }
}

// ---------------------------------------------------------------------------
// Kernel 3 (R23): out^T bf16 MFMA GEMM, tile shrunk 128x128 -> 64feat x
// 128tok => grid 8x64 = 512 blocks = 2 blocks/CU (was 1: 1 wave/SIMD, the
// worst TLP in the pipeline; never profiled because always below top-5).
// Chunk = A 4KB + B 8KB = 12KB; QUAD-buffered = 49152 B (fits 3 blocks/CU,
// grid-capped at 2). 3-chunk-deep prefetch, counted vmcnt(6) (3 DMAs/wave
// per chunk). Same verified fragment/epilogue mapping, A-repeat i<2.
// ---------------------------------------------------------------------------
__global__ __launch_bounds__(256, 2) void out_gemm_mfma(
    const ushort* __restrict__ Ag, const ushort* __restrict__ Bg,
    const float* __restrict__ bias, float* __restrict__ out)
{
    extern __shared__ __align__(16) char smem[];   // 49152 B (4 x 12288)

    const int tid  = threadIdx.x;
    const int lane = tid & 63;
    const int w    = tid >> 6;
    const int c    = lane & 15;
    const int quad = lane >> 4;
    const int wr   = w >> 1, wc = w & 1;
    const int tn   = blockIdx.x;   // token tile (64 of 128)
    const int tf   = blockIdx.y;   // feature tile (8 of 64)

    f32x4 acc[2][4] = {};

    // staging: 12 segs of 1KB per chunk (segs 0-3 = A 64feat, 4-11 = B
    // 128tok); wave w issues segs 3w..3w+2
    auto stage = [&](int k0, int buf) {
#pragma unroll
        for (int g = 0; g < 3; g++) {
            const int s = w*3 + g;             // 0..11
            const ushort* src;
            int dst;
            if (s < 4) {
                src = Ag + (size_t)(tf*64 + s*16 + c)*INNER + k0 + quad*8;
                dst = buf*12288 + s*1024;
            } else {
                src = Bg + (size_t)(tn*128 + (s-4)*16 + c)*INNER + k0 + quad*8;
                dst = buf*12288 + 4096 + (s-4)*1024;
            }
            async16(src, smem + dst);
        }
    };

    stage(0, 0);
    stage(32, 1);
    stage(64, 2);

    for (int ch = 0; ch < 16; ch++) {
        const int cur = ch & 3;
        // outstanding before wait: min(3,16-ch) chunks x 3 DMAs
        if (ch <= 13) {
            __asm__ volatile("s_waitcnt vmcnt(6)\n\ts_barrier" ::: "memory");
        } else if (ch == 14) {
            __asm__ volatile("s_waitcnt vmcnt(3)\n\ts_barrier" ::: "memory");
        } else {
            __asm__ volatile("s_waitcnt vmcnt(0)\n\ts_barrier" ::: "memory");
        }
        if (ch < 13) stage((ch+3)*32, (ch+3) & 3);

        const char* B = smem + cur*12288;
        bf16x8 fa[2], fb[4];
#pragma unroll
        for (int i = 0; i < 2; i++)
            fa[i] = *(const bf16x8*)(B + (wr*2 + i)*1024 + lane*16);
#pragma unroll
        for (int j = 0; j < 4; j++)
            fb[j] = *(const bf16x8*)(B + 4096 + (wc*4 + j)*1024 + lane*16);
#pragma unroll
        for (int i = 0; i < 2; i++)
#pragma unroll
            for (int j = 0; j < 4; j++)
                acc[i][j] = __builtin_amdgcn_mfma_f32_16x16x32_bf16(
                    fa[i], fb[j], acc[i][j], 0, 0, 0);
        // no trailing barrier (4-buffer rotation gates reuse via top barrier)
    }

#pragma unroll
    for (int j = 0; j < 4; j++) {
        const int tc = tn*128 + wc*64 + j*16 + c;
#pragma unroll
        for (int i = 0; i < 2; i++) {
            const int fr = tf*64 + wr*32 + i*16 + quad*4;
            float4 bv = *(const float4*)(bias + fr);
            float4 ov = { acc[i][j][0] + bv.x, acc[i][j][1] + bv.y,
                          acc[i][j][2] + bv.z, acc[i][j][3] + bv.w };
            *(float4*)(out + (size_t)tc*DIM + fr) = ov;
        }
    }
}

extern "C" void kernel_launch(void* const* d_in, const int* in_sizes, int n_in,
                              void* d_out, int out_size, void* d_ws, size_t ws_size,
                              hipStream_t stream) {
    (void)in_sizes; (void)n_in; (void)out_size; (void)ws_size;
    const float* x     = (const float*)d_in[0];
    const float* rot   = (const float*)d_in[1];
    const float* trans = (const float*)d_in[2];
    const float* w_qkv = (const float*)d_in[3];
    const float* b_qkv = (const float*)d_in[4];
    const float* w_out = (const float*)d_in[5];
    const float* b_out = (const float*)d_in[6];
    float* out = (float*)d_out;

    const size_t HB = (size_t)BSZ*NH*NSEQ*DH;        // 4,194,304 elements
    ushort* qb   = (ushort*)d_ws;
    ushort* kb   = qb   + HB;
    ushort* vt   = kb   + HB;                        // [BH][DH][NSEQ]
    ushort* woTh = vt   + HB;                        // [DIM][INNER] bf16
    ushort* wqTh = woTh + (size_t)DIM*INNER;         // [QKVN][DIM] fp16
    ushort* xf   = wqTh + (size_t)QKVN*DIM;          // [NTOK][DIM] fp16
    // om reuses xf (x consumed by kernel 1; om written by kernel 2)
    ushort* om   = xf;

    prep_kernel<<<dim3(5120), 256, 0, stream>>>(
        x, xf, w_qkv, wqTh, w_out, woTh);

    qkv_gemm_f16<<<dim3(NTOK/128, QKVN/128), 256, 32768, stream>>>(
        wqTh, xf, b_qkv, rot, trans, qb, kb, vt);
    attn_mfma_kernel<<<dim3(1024), 256, 0, stream>>>(
        qb, kb, vt, rot, trans, om);
    out_gemm_mfma<<<dim3(NTOK/128, DIM/64), 256, 49152, stream>>>(
        woTh, om, b_out, out);
}

// Round 12
// 166.957 us; speedup vs baseline: 1.0220x; 1.0220x over previous
//
#include <hip/hip_runtime.h>
#include <math.h>

#define BSZ   8
#define NSEQ  1024
#define DIM   512
#define NH    8
#define DH    64
#define INNER 512
#define NTOK  (BSZ*NSEQ)     // 8192
#define QKVN  (3*INNER)      // 1536

typedef __bf16   bf16x8 __attribute__((ext_vector_type(8)));
typedef _Float16 f16x8  __attribute__((ext_vector_type(8)));
typedef float    f32x4  __attribute__((ext_vector_type(4)));
typedef unsigned u32x4  __attribute__((ext_vector_type(4)));

// q pre-scale: softmax scale (DH^-0.5 = 0.125) folded with log2(e)
#define QSCL (0.125f * 1.44269504088896f)

static __device__ __forceinline__ ushort f2bf(float f) {
    union { float f; unsigned u; } v; v.f = f;
    unsigned r = (v.u + 0x7FFFu + ((v.u >> 16) & 1u)) >> 16;  // RNE
    return (ushort)r;
}
static __device__ __forceinline__ ushort f2h(float f) {
    _Float16 h = (_Float16)f;                                  // RNE
    return __builtin_bit_cast(unsigned short, h);
}
// async global->LDS DMA, 16B per lane; LDS dest = wave-uniform base + lane*16
static __device__ __forceinline__ void async16(const void* g, void* l) {
    __builtin_amdgcn_global_load_lds(
        (const __attribute__((address_space(1))) unsigned int*)g,
        (__attribute__((address_space(3))) unsigned int*)l, 16, 0, 0);
}

// ---------------------------------------------------------------------------
// Fused prep kernel: one dispatch.
//   blocks [0,4096):    x fp32 -> fp16
//   blocks [4096,4864): w_qkv [DIM][QKVN] -> wqT fp16 [QKVN][DIM]
//   blocks [4864,5120): w_out [INNER][DIM] -> woT bf16 [DIM][INNER]
// ---------------------------------------------------------------------------
__global__ __launch_bounds__(256) void prep_kernel(
    const float* __restrict__ x,  ushort* __restrict__ xf,
    const float* __restrict__ wq, ushort* __restrict__ wqT,
    const float* __restrict__ wo, ushort* __restrict__ woT)
{
    const int bid = blockIdx.x;
    if (bid < 4096) {
        const int i = bid*256 + threadIdx.x;
        float4 v = ((const float4*)x)[i];
        ushort4 h = { f2h(v.x), f2h(v.y), f2h(v.z), f2h(v.w) };
        ((ushort4*)xf)[i] = h;
        return;
    }
    __shared__ float tile[32][33];
    int K, F, bx, by; const float* in; ushort* outp; int is_q;
    if (bid < 4096 + 768) {
        const int id = bid - 4096;
        bx = id % 48; by = id / 48;          // F/32=48, K/32=16
        K = DIM; F = QKVN; in = wq; outp = wqT; is_q = 1;
    } else {
        const int id = bid - 4864;
        bx = id % 16; by = id / 16;          // F/32=16, K/32=16
        K = INNER; F = DIM; in = wo; outp = woT; is_q = 0;
    }
    const int lx = threadIdx.x & 31, ly = threadIdx.x >> 5;
#pragma unroll
    for (int u = 0; u < 4; u++) {
        const int k = by*32 + ly + u*8;
        tile[ly + u*8][lx] = in[(size_t)k*F + bx*32 + lx];
    }
    __syncthreads();
#pragma unroll
    for (int u = 0; u < 4; u++) {
        const int f = bx*32 + ly + u*8;
        const float v = tile[lx][ly + u*8];
        outp[(size_t)f*K + by*32 + lx] = is_q ? f2h(v) : f2bf(v);
    }
}

// ---------------------------------------------------------------------------
// Kernel 1 (R16 exact, kept): qkv^T fp16 GEMM, DOUBLE-buffered LDS
// (2 x 16384 = 32768 B), BK=32, stage-before-wait, per-wave vmcnt(4).
// Epilogue: bias + SE(3) pose.
// ---------------------------------------------------------------------------
__global__ __launch_bounds__(256) void qkv_gemm_f16(
    const ushort* __restrict__ Ag,   // wqT fp16 [QKVN][DIM]
    const ushort* __restrict__ Bg,   // x   fp16 [NTOK][DIM]
    const float* __restrict__ bias, const float* __restrict__ rot,
    const float* __restrict__ trans,
    ushort* __restrict__ qb, ushort* __restrict__ kb, ushort* __restrict__ vt)
{
    extern __shared__ __align__(16) char smem[];   // 32768 B

    const int tid  = threadIdx.x;
    const int lane = tid & 63;
    const int w    = tid >> 6;
    const int c    = lane & 15;
    const int quad = lane >> 4;
    const int wr   = w >> 1, wc = w & 1;
    const int tn   = blockIdx.x;   // token tile (64)
    const int tf   = blockIdx.y;   // feature tile (12)

    f32x4 acc[4][4] = {};

    // staging roles: part = w>>1 (0=A,1=B), group base = (w&1)*4
    const int part = w >> 1;
    const int g0   = (w & 1) * 4;
    const ushort* src = (part == 0) ? Ag : Bg;
    const ushort* wbase = src + (size_t)((part == 0 ? tf : tn)*128 + g0*16 + c)*DIM
                          + quad*8;

    auto stage = [&](int k0, int buf) {
#pragma unroll
        for (int g = 0; g < 4; g++)
            async16(wbase + (size_t)g*16*DIM + k0,
                    smem + buf*16384 + part*8192 + (g0 + g)*1024);
    };

    stage(0, 0);

    for (int ch = 0; ch < 16; ch++) {
        const int cur = ch & 1, nxt = cur ^ 1;
        if (ch < 15) {
            stage((ch+1)*32, nxt);
            // wait own chunk-ch's 4 DMAs (oldest); ch+1's 4 stay in flight
            __asm__ volatile("s_waitcnt vmcnt(4)\n\ts_barrier" ::: "memory");
        } else {
            __asm__ volatile("s_waitcnt vmcnt(0)\n\ts_barrier" ::: "memory");
        }

        const char* B = smem + cur*16384;
        f16x8 fa[4], fb[4];
#pragma unroll
        for (int i = 0; i < 4; i++)
            fa[i] = *(const f16x8*)(B + (wr*4 + i)*1024 + lane*16);
#pragma unroll
        for (int j = 0; j < 4; j++)
            fb[j] = *(const f16x8*)(B + 8192 + (wc*4 + j)*1024 + lane*16);
#pragma unroll
        for (int i = 0; i < 4; i++)
#pragma unroll
            for (int j = 0; j < 4; j++)
                acc[i][j] = __builtin_amdgcn_mfma_f32_16x16x32_f16(
                    fa[i], fb[j], acc[i][j], 0, 0, 0);
        __asm__ volatile("s_waitcnt lgkmcnt(0)\n\ts_barrier" ::: "memory");
    }

    // epilogue: bias + SE(3) pose + scatter (verified mapping, unchanged)
    const int sec = tf >> 2;          // 0=q 1=k 2=v (block-uniform)

#pragma unroll
    for (int j = 0; j < 4; j++) {
        const int tc = tn*128 + wc*64 + j*16 + c;
        const int bb = tc >> 10, n = tc & 1023;
        const float* R = rot   + (size_t)(bb*NSEQ + n)*9;
        const float* T = trans + (size_t)(bb*NSEQ + n)*3;
        const float R0=R[0],R1=R[1],R2=R[2],R3=R[3],R4=R[4],R5=R[5],R6=R[6],R7=R[7],R8=R[8];
        const float T0=T[0],T1=T[1],T2=T[2];
        float ti0 = 0.f, ti1 = 0.f, ti2 = 0.f;
        if (sec == 0) {
            ti0 = -(R0*T0 + R3*T1 + R6*T2);
            ti1 = -(R1*T0 + R4*T1 + R7*T2);
            ti2 = -(R2*T0 + R5*T1 + R8*T2);
        }
#pragma unroll
        for (int i = 0; i < 4; i++) {
            const int fr = tf*128 + wr*64 + i*16 + quad*4;
            const int fl = fr & 511;
            const int h  = fl >> 6, d = fl & 63;
            float4 bv = *(const float4*)(bias + fr);
            const float g0v = acc[i][j][0] + bv.x;
            const float g1v = acc[i][j][1] + bv.y;
            const float g2v = acc[i][j][2] + bv.z;
            const float g3v = acc[i][j][3] + bv.w;
            if (sec == 0) {
                float o0 = (R0*g0v + R1*g1v + R2*g2v) * QSCL;
                float o1 = (R3*g0v + R4*g1v + R5*g2v) * QSCL;
                float o2 = (R6*g0v + R7*g1v + R8*g2v) * QSCL;
                float o3 = (ti0*g0v + ti1*g1v + ti2*g2v + g3v) * QSCL;
                ushort4 ov = { f2bf(o0), f2bf(o1), f2bf(o2), f2bf(o3) };
                *(ushort4*)(qb + ((size_t)((bb*NH + h)*NSEQ + n))*DH + d) = ov;
            } else {
                float o0 = R0*g0v + R1*g1v + R2*g2v + T0*g3v;
                float o1 = R3*g0v + R4*g1v + R5*g2v + T1*g3v;
                float o2 = R6*g0v + R7*g1v + R8*g2v + T2*g3v;
                float o3 = g3v;
                if (sec == 1) {
                    ushort4 ov = { f2bf(o0), f2bf(o1), f2bf(o2), f2bf(o3) };
                    *(ushort4*)(kb + ((size_t)((bb*NH + h)*NSEQ + n))*DH + d) = ov;
                } else {
                    // v: write TRANSPOSED -> vt[bh][d][n]
                    ushort* vtb = vt + ((size_t)(bb*NH + h)*DH + d)*NSEQ + n;
                    vtb[0*NSEQ] = f2bf(o0);
                    vtb[1*NSEQ] = f2bf(o1);
                    vtb[2*NSEQ] = f2bf(o2);
                    vtb[3*NSEQ] = f2bf(o3);
                }
            }
        }
    }
}

// ---------------------------------------------------------------------------
// Kernel 2 (R24): T12 full in-register P — NO P-LDS region.
// Keeps R21/R22's proven schedule (triple-buffer KV, ONE barrier/iter,
// counted vmcnt(4), 2-deep prefetch, grid 1024 + XCD swizzle) and R22's
// VERIFIED swapped-QK^T layout: lane (c,quad) reg r = S[key=nt*16+quad*4+r]
// [q=c]. New: P packed via v_cvt_pk_bf16_f32 and moved to the PV A-fragment
// lanes with __shfl (ds_bpermute crossbar, no LDS storage, no barrier):
//   A-frag elem j of lane (c,quad), kc2: src lane = c + 32*(quad&1) +
//   16*(j>>2); u32 slot (j>>1)&1; nt = kc2*2 + (quad>>1) (2-candidate
//   shuffle + select => static register indexing).
// Deletes: 16 ds_write + lgkmcnt(0) + 2 ds_read per iter AND the 9216 B
// P region => LDS 58368 -> 49408 B => 3 blocks/CU (12 waves, +50% TLP).
// lsum: R22's verified scalar path (q = lane's c), parked in 256 B LDS.
// ---------------------------------------------------------------------------
__global__ __launch_bounds__(256, 3) void attn_mfma_kernel(
    const ushort* __restrict__ qb, const ushort* __restrict__ kb,
    const ushort* __restrict__ vt, const float* __restrict__ rot,
    const float* __restrict__ trans, ushort* __restrict__ om)
{
    __shared__ __align__(16) char smem[49408];   // KV 3x16384 + lsum 256

    const int tid  = threadIdx.x;
    const int lane = tid & 63;
    const int w    = tid >> 6;
    const int c    = lane & 15;
    const int quad = lane >> 4;

    // XCD-aware swizzle (nwg=1024, %8==0 -> bijective); 8 bh per XCD
    const int o   = blockIdx.x;               // 0..1023
    const int wid = (o & 7) * 128 + (o >> 3);
    const int qt  = wid & 15;                 // 0..15 (64 q rows each)
    const int bh  = wid >> 4;                 // 0..63
    const int bb = bh >> 3, h = bh & 7;

    const ushort* Q = qb + (size_t)bh * NSEQ * DH;
    const ushort* K = kb + (size_t)bh * NSEQ * DH;
    const ushort* V = vt + (size_t)bh * DH * NSEQ;   // [DH][NSEQ]

    // wave w owns q rows [qt*64 + w*16, +16)
    bf16x8 qf[2];
    {
        const ushort* qrow = Q + (size_t)(qt*64 + w*16 + c)*DH + quad*8;
        qf[0] = *(const bf16x8*)(qrow);
        qf[1] = *(const bf16x8*)(qrow + 32);
    }

    f32x4 Oacc[4] = {};
    float lsum = 0.f;

    // stage one 64-key chunk: 8 K segs + 8 V segs of 1024B; wave w issues
    // 2 of each (4 DMAs total per wave per chunk)
    auto stage = [&](int kt, int buf) {
#pragma unroll
        for (int u = 0; u < 2; u++) {            // K segs
            const int seg = w + u*4;             // 0..7
            const int nt = seg >> 1, hh = seg & 1;
            const ushort* g = K + (size_t)(kt*64 + nt*16 + c)*DH + hh*32 + quad*8;
            async16(g, smem + buf*16384 + seg*1024);
        }
#pragma unroll
        for (int u = 0; u < 2; u++) {            // V segs
            const int s2 = w + u*4;              // 0..7
            const int nt = s2 >> 1, kc = s2 & 1;
            const ushort* g = V + (size_t)(nt*16 + c)*NSEQ + kt*64 + kc*32 + quad*8;
            async16(g, smem + buf*16384 + 8192 + s2*1024);
        }
    };

    stage(0, 0);
    stage(1, 1);

    float* lsumS = (float*)(smem + 49152);       // [64] per-q sums

    for (int kt = 0; kt < 16; kt++) {
        const int cur = kt % 3;
        // own chunk-kt's 4 DMAs (oldest) done; kt+1's 4 stay in flight
        if (kt < 15) {
            __asm__ volatile("s_waitcnt vmcnt(4)\n\ts_barrier" ::: "memory");
        } else {
            __asm__ volatile("s_waitcnt vmcnt(0)\n\ts_barrier" ::: "memory");
        }
        // buf (kt+2)%3 == (kt-1)%3: its reads were consumed before
        // barrier(kt)
        if (kt < 14) stage(kt + 2, (kt + 2) % 3);

        const char* Kb = smem + cur*16384;
        const char* Vb = smem + cur*16384 + 8192;

        // SWAPPED QK^T (R22-verified): lane (c,quad) reg r =
        // S[key = nt*16 + quad*4 + r][q = c]
        f32x4 s[4];
#pragma unroll
        for (int nt = 0; nt < 4; nt++) {
            bf16x8 k0 = *(const bf16x8*)(Kb + (nt*2+0)*1024 + lane*16);
            bf16x8 k1 = *(const bf16x8*)(Kb + (nt*2+1)*1024 + lane*16);
            f32x4 a = {0.f, 0.f, 0.f, 0.f};
            a = __builtin_amdgcn_mfma_f32_16x16x32_bf16(k0, qf[0], a, 0, 0, 0);
            a = __builtin_amdgcn_mfma_f32_16x16x32_bf16(k1, qf[1], a, 0, 0, 0);
            s[nt] = a;
        }

        // exp2 + pack to bf16 pairs (stays in registers)
        unsigned lo[4], hi[4];
#pragma unroll
        for (int nt = 0; nt < 4; nt++) {
            const float p0 = exp2f(s[nt][0]);
            const float p1 = exp2f(s[nt][1]);
            const float p2 = exp2f(s[nt][2]);
            const float p3 = exp2f(s[nt][3]);
            lsum += (p0 + p1) + (p2 + p3);
            __asm__("v_cvt_pk_bf16_f32 %0, %1, %2" : "=v"(lo[nt]) : "v"(p0), "v"(p1));
            __asm__("v_cvt_pk_bf16_f32 %0, %1, %2" : "=v"(hi[nt]) : "v"(p2), "v"(p3));
        }

        // cross-lane redistribution to PV A-fragments + PV MFMA
        const int sA = (quad & 1) * 32 + c;      // src lane, quad_s=(quad&1)*2
        const int sB = sA + 16;                  // quad_s+1
        const bool hiq = (quad >> 1) != 0;       // selects nt candidate
#pragma unroll
        for (int kc2 = 0; kc2 < 2; kc2++) {
            const int n0 = kc2*2, n1 = kc2*2 + 1;
            unsigned a0 = __shfl(lo[n0], sA), b0 = __shfl(lo[n1], sA);
            unsigned a1 = __shfl(hi[n0], sA), b1 = __shfl(hi[n1], sA);
            unsigned a2 = __shfl(lo[n0], sB), b2 = __shfl(lo[n1], sB);
            unsigned a3 = __shfl(hi[n0], sB), b3 = __shfl(hi[n1], sB);
            u32x4 av = { hiq ? b0 : a0, hiq ? b1 : a1,
                         hiq ? b2 : a2, hiq ? b3 : a3 };
            bf16x8 a = __builtin_bit_cast(bf16x8, av);

            bf16x8 vfr[4];
#pragma unroll
            for (int nt = 0; nt < 4; nt++)
                vfr[nt] = *(const bf16x8*)(Vb + (nt*2+kc2)*1024 + lane*16);
#pragma unroll
            for (int nt = 0; nt < 4; nt++)
                Oacc[nt] = __builtin_amdgcn_mfma_f32_16x16x32_bf16(
                    a, vfr[nt], Oacc[nt], 0, 0, 0);
        }
        // no trailing barrier: 3-buffer rotation gates KV reuse via the
        // top-of-loop barrier two iterations from now
    }

    // per-q row sum (R22-verified): lane (c,quad) has partial over its keys
    lsum += __shfl_xor(lsum, 16);
    lsum += __shfl_xor(lsum, 32);
    if (lane < 16) lsumS[w*16 + c] = lsum;     // q = w*16 + c

    __syncthreads();
    float (*Osh)[68] = (float (*)[68])smem;   // [64][68] = 17408 B overlay
#pragma unroll
    for (int nt = 0; nt < 4; nt++)
#pragma unroll
        for (int r = 0; r < 4; r++)
            Osh[w*16 + quad*4 + r][nt*16 + c] = Oacc[nt][r];   // unnormalized
    __syncthreads();

#pragma unroll
    for (int u = 0; u < 4; u++) {
        const int t   = tid + u*256;       // 0..1023
        const int row = t >> 4;            // 0..63
        const int g   = t & 15;
        const int n   = qt*64 + row;
        const float inv = 1.f / lsumS[row];
        const float o0 = Osh[row][g*4+0] * inv, o1 = Osh[row][g*4+1] * inv;
        const float o2 = Osh[row][g*4+2] * inv, o3 = Osh[row][g*4+3] * inv;
        const float* R = rot   + (size_t)(bb*NSEQ + n)*9;
        const float* T = trans + (size_t)(bb*NSEQ + n)*3;
        const float ti0 = -(R[0]*T[0] + R[3]*T[1] + R[6]*T[2]);
        const float ti1 = -(R[1]*T[0] + R[4]*T[1] + R[7]*T[2]);
        const float ti2 = -(R[2]*T[0] + R[5]*T[1] + R[8]*T[2]);
        const float p0 = R[0]*o0 + R[3]*o1 + R[6]*o2 + ti0*o3;
        const float p1 = R[1]*o0 + R[4]*o1 + R[7]*o2 + ti1*o3;
        const float p2 = R[2]*o0 + R[5]*o1 + R[8]*o2 + ti2*o3;
        const float p3 = o3;
        ushort4 hv = { f2bf(p0), f2bf(p1), f2bf(p2), f2bf(p3) };
        *(ushort4*)(om + (size_t)(bb*NSEQ + n)*INNER + h*DH + g*4) = hv;
    }
}

// ---------------------------------------------------------------------------
// Kernel 3 (reverted to the best-total config's version): out^T bf16 MFMA
// GEMM, 128x128 tile, QUAD-buffered LDS (4 x 16384 = 65536 B), ONE barrier
// per chunk, 3-chunk-deep prefetch. Epilogue: + bias, fp32 store.
// ---------------------------------------------------------------------------
__global__ __launch_bounds__(256) void out_gemm_mfma(
    const ushort* __restrict__ Ag, const ushort* __restrict__ Bg,
    const float* __restrict__ bias, float* __restrict__ out)
{
    extern __shared__ __align__(16) char smem[];   // 65536 B

    const int tid  = threadIdx.x;
    const int lane = tid & 63;
    const int w    = tid >> 6;
    const int c    = lane & 15;
    const int quad = lane >> 4;
    const int wr   = w >> 1, wc = w & 1;
    const int tn   = blockIdx.x;   // token tile (64)
    const int tf   = blockIdx.y;   // feature tile (4)

    f32x4 acc[4][4] = {};

    // staging roles: part = w>>1 (0=A,1=B), group base = (w&1)*4
    const int part = w >> 1;
    const int g0   = (w & 1) * 4;
    const ushort* src = (part == 0) ? Ag : Bg;
    const ushort* wbase = src + (size_t)((part == 0 ? tf : tn)*128 + g0*16 + c)*INNER
                          + quad*8;

    auto stage = [&](int k0, int buf) {
#pragma unroll
        for (int g = 0; g < 4; g++)
            async16(wbase + (size_t)g*16*INNER + k0,
                    smem + buf*16384 + part*8192 + (g0 + g)*1024);
    };

    stage(0, 0);
    stage(32, 1);
    stage(64, 2);

    for (int ch = 0; ch < 16; ch++) {
        const int cur = ch & 3;
        // chunks in flight after the wait: min(3, 15-ch); 4 DMAs each
        if (ch < 14) {
            __asm__ volatile("s_waitcnt vmcnt(8)\n\ts_barrier" ::: "memory");
        } else if (ch == 14) {
            __asm__ volatile("s_waitcnt vmcnt(4)\n\ts_barrier" ::: "memory");
        } else {
            __asm__ volatile("s_waitcnt vmcnt(0)\n\ts_barrier" ::: "memory");
        }
        if (ch < 13) stage((ch+3)*32, (ch+3) & 3);

        const char* B = smem + cur*16384;
        bf16x8 fa[4], fb[4];
#pragma unroll
        for (int i = 0; i < 4; i++)
            fa[i] = *(const bf16x8*)(B + (wr*4 + i)*1024 + lane*16);
#pragma unroll
        for (int j = 0; j < 4; j++)
            fb[j] = *(const bf16x8*)(B + 8192 + (wc*4 + j)*1024 + lane*16);
#pragma unroll
        for (int i = 0; i < 4; i++)
#pragma unroll
            for (int j = 0; j < 4; j++)
                acc[i][j] = __builtin_amdgcn_mfma_f32_16x16x32_bf16(
                    fa[i], fb[j], acc[i][j], 0, 0, 0);
        // no trailing barrier (4-buffer rotation gates reuse via top barrier)
    }

#pragma unroll
    for (int j = 0; j < 4; j++) {
        const int tc = tn*128 + wc*64 + j*16 + c;
#pragma unroll
        for (int i = 0; i < 4; i++) {
            const int fr = tf*128 + wr*64 + i*16 + quad*4;
            float4 bv = *(const float4*)(bias + fr);
            float4 ov = { acc[i][j][0] + bv.x, acc[i][j][1] + bv.y,
                          acc[i][j][2] + bv.z, acc[i][j][3] + bv.w };
            *(float4*)(out + (size_t)tc*DIM + fr) = ov;
        }
    }
}

extern "C" void kernel_launch(void* const* d_in, const int* in_sizes, int n_in,
                              void* d_out, int out_size, void* d_ws, size_t ws_size,
                              hipStream_t stream) {
    (void)in_sizes; (void)n_in; (void)out_size; (void)ws_size;
    const float* x     = (const float*)d_in[0];
    const float* rot   = (const float*)d_in[1];
    const float* trans = (const float*)d_in[2];
    const float* w_qkv = (const float*)d_in[3];
    const float* b_qkv = (const float*)d_in[4];
    const float* w_out = (const float*)d_in[5];
    const float* b_out = (const float*)d_in[6];
    float* out = (float*)d_out;

    const size_t HB = (size_t)BSZ*NH*NSEQ*DH;        // 4,194,304 elements
    ushort* qb   = (ushort*)d_ws;
    ushort* kb   = qb   + HB;
    ushort* vt   = kb   + HB;                        // [BH][DH][NSEQ]
    ushort* woTh = vt   + HB;                        // [DIM][INNER] bf16
    ushort* wqTh = woTh + (size_t)DIM*INNER;         // [QKVN][DIM] fp16
    ushort* xf   = wqTh + (size_t)QKVN*DIM;          // [NTOK][DIM] fp16
    // om reuses xf (x consumed by kernel 1; om written by kernel 2)
    ushort* om   = xf;

    // dynamic-LDS opt-in for >=64KB — host-side attribute set, idempotent.
    static int s_attr_done = 0;
    if (!s_attr_done) {
        (void)hipFuncSetAttribute((const void*)out_gemm_mfma,
            hipFuncAttributeMaxDynamicSharedMemorySize, 65536);
        s_attr_done = 1;
    }

    prep_kernel<<<dim3(5120), 256, 0, stream>>>(
        x, xf, w_qkv, wqTh, w_out, woTh);

    qkv_gemm_f16<<<dim3(NTOK/128, QKVN/128), 256, 32768, stream>>>(
        wqTh, xf, b_qkv, rot, trans, qb, kb, vt);
    attn_mfma_kernel<<<dim3(1024), 256, 0, stream>>>(
        qb, kb, vt, rot, trans, om);
    out_gemm_mfma<<<dim3(NTOK/128, DIM/128), 256, 65536, stream>>>(
        woTh, om, b_out, out);
}